// Round 1
// baseline (1028.124 us; speedup 1.0000x reference)
//
#include <hip/hip_runtime.h>

#define BB 64
#define TT 1024
#define HH 1024
#define II 8
#define OO 8
#define RRK 4
#define NOISE_STD 0.05f
#define ALPHA 0.2f

// DPP-based add: acc + dpp_perm(src). VALU pipe (NOT ds_bpermute like __shfl).
template<int CTRL, int RM>
__device__ __forceinline__ float dpp_add(float acc, float src) {
    int s = __builtin_amdgcn_update_dpp(0, __float_as_int(src), CTRL, RM, 0xF, true);
    return acc + __int_as_float(s);
}

// Full wave64 sum; result valid on lane 63.
__device__ __forceinline__ float wave_sum(float x) {
    x = dpp_add<0xB1, 0xF>(x, x);   // xor 1
    x = dpp_add<0x4E, 0xF>(x, x);   // xor 2
    x = dpp_add<0x141, 0xF>(x, x);  // row_half_mirror
    x = dpp_add<0x140, 0xF>(x, x);  // row_mirror
    x = dpp_add<0x142, 0xA>(x, x);  // row_bcast:15
    x = dpp_add<0x143, 0xC>(x, x);  // row_bcast:31
    return x;
}

// tanh(x) = 1 - 2/(1 + e^{2x}); argument passed as 2x.
__device__ __forceinline__ float tanh_from_2x(float two_x) {
    float e = __expf(two_x);
    float r = __builtin_amdgcn_rcpf(e + 1.0f);
    return fmaf(-2.0f, r, 1.0f);
}

// Barrier WITHOUT the vmcnt(0) drain of __syncthreads(): waits only LDS ops.
__device__ __forceinline__ void block_sync_lds() {
    asm volatile("s_waitcnt lgkmcnt(0)\n\ts_barrier" ::: "memory");
}

// ---------------------------------------------------------------------------
// Single fused kernel: one block per batch.
// The former prew pre-pass (W[b,t,o] = sigma * noise[b,t,:] @ (wo*so)) is
// folded into the t-loop: noise rows are already in registers (nzb) for the
// h-update, so the 8 extra wave_sums reuse the same data and the same
// cross-wave LDS reduction machinery. They are scheduled AFTER the barrier
// (in the shadow of the red_v ds_read latency) and consumed one step late
// by the y-recurrence (y feeds nothing back into h, so it may lag freely).
// ---------------------------------------------------------------------------
__global__ __launch_bounds__(256, 1)
void rnn_seq_kernel(const float* __restrict__ x, const float* __restrict__ noise,
                    const float* __restrict__ wi, const float* __restrict__ si,
                    const float* __restrict__ mM, const float* __restrict__ nM,
                    const float* __restrict__ bv, const float* __restrict__ wo,
                    const float* __restrict__ so, const float* __restrict__ h0,
                    float* __restrict__ out) {
    __shared__ __align__(16) float lds_x[TT * II];    // 32 KB
    __shared__ __align__(16) float lds_out[TT * OO];  // 32 KB
    __shared__ __align__(16) float red[4][4][4];      // ring x wave x q   (v partials)
    __shared__ __align__(16) float red_w[4][4][8];    // ring x wave x o   (noise@wo partials)
    __shared__ __align__(16) float redc[4][104];      // preamble scratch (wave-major)
    __shared__ float ambx[104];                       // Am(32) | Bx(64) | y0(8)

    const int tid  = threadIdx.x;
    const int b    = blockIdx.x;
    const int wave = tid >> 6;
    const int lane = tid & 63;
    const int e0   = tid << 2;
    const int oc   = tid & 7;                         // this thread's o-column for y

    // ---- stage x[b] into LDS ----
    {
        const float4* sx = (const float4*)(x + (size_t)b * (TT * II));
        float4* dx = (float4*)lds_x;
        #pragma unroll
        for (int k = 0; k < 8; ++k)
            dx[k * 256 + tid] = sx[k * 256 + tid];
    }

    // ---- fold constants into registers ----
    float wia[II][4];                                  // ALPHA*si[i]*wi[i][h_e]
    #pragma unroll
    for (int i = 0; i < II; ++i) {
        const float s  = ALPHA * si[i];
        const float4 w = *(const float4*)(wi + i * HH + e0);
        wia[i][0] = w.x * s; wia[i][1] = w.y * s; wia[i][2] = w.z * s; wia[i][3] = w.w * s;
    }
    float ma[4][RRK], nr[4][RRK];
    #pragma unroll
    for (int e = 0; e < 4; ++e) {
        const float4 m4 = *(const float4*)(mM + (e0 + e) * RRK);
        const float4 n4 = *(const float4*)(nM + (e0 + e) * RRK);
        const float cs = ALPHA / (float)HH;            // fold ALPHA/H into m
        ma[e][0] = m4.x * cs; ma[e][1] = m4.y * cs; ma[e][2] = m4.z * cs; ma[e][3] = m4.w * cs;
        nr[e][0] = n4.x; nr[e][1] = n4.y; nr[e][2] = n4.z; nr[e][3] = n4.w;
    }
    float woa[4][OO];                                  // wo[h_e][o]*so[o]  (loop-resident now)
    {
        float so8[OO];
        #pragma unroll
        for (int o = 0; o < OO; ++o) so8[o] = so[o];
        #pragma unroll
        for (int e = 0; e < 4; ++e) {
            const float4 a4 = *(const float4*)(wo + (e0 + e) * OO);
            const float4 b4 = *(const float4*)(wo + (e0 + e) * OO + 4);
            woa[e][0] = a4.x * so8[0]; woa[e][1] = a4.y * so8[1];
            woa[e][2] = a4.z * so8[2]; woa[e][3] = a4.w * so8[3];
            woa[e][4] = b4.x * so8[4]; woa[e][5] = b4.y * so8[5];
            woa[e][6] = b4.z * so8[6]; woa[e][7] = b4.w * so8[7];
        }
    }
    float tb2[4], h[4], r[4];
    {
        const float4 b4 = *(const float4*)(bv + e0);
        tb2[0] = 2.f * b4.x; tb2[1] = 2.f * b4.y; tb2[2] = 2.f * b4.z; tb2[3] = 2.f * b4.w;
        const float4 h4 = *(const float4*)(h0 + e0);
        h[0] = h4.x; h[1] = h4.y; h[2] = h4.z; h[3] = h4.w;
        #pragma unroll
        for (int e = 0; e < 4; ++e) r[e] = tanh_from_2x(2.f * h[e]);
    }

    // ---- preamble: reduce Am (4x8), Bx (8x8), y0 (8) from register-folded weights ----
    #pragma unroll
    for (int kg = 0; kg < 26; ++kg) {
        float p[4];
        #pragma unroll
        for (int u = 0; u < 4; ++u) {
            const int k = kg * 4 + u;
            float s;
            if (k < 32) {
                const int q = k >> 3, o = k & 7;
                s = fmaf(ma[0][q], woa[0][o], fmaf(ma[1][q], woa[1][o],
                    fmaf(ma[2][q], woa[2][o], ma[3][q] * woa[3][o])));
            } else if (k < 96) {
                const int i = (k - 32) >> 3, o = k & 7;
                s = fmaf(wia[i][0], woa[0][o], fmaf(wia[i][1], woa[1][o],
                    fmaf(wia[i][2], woa[2][o], wia[i][3] * woa[3][o])));
            } else {
                const int o = k - 96;
                s = fmaf(h[0], woa[0][o], fmaf(h[1], woa[1][o],
                    fmaf(h[2], woa[2][o], h[3] * woa[3][o])));
            }
            p[u] = wave_sum(s);
        }
        if (lane == 63)
            *(float4*)&redc[wave][kg * 4] = make_float4(p[0], p[1], p[2], p[3]);
    }
    block_sync_lds();
    if (tid < 104)
        ambx[tid] = (redc[0][tid] + redc[1][tid]) + (redc[2][tid] + redc[3][tid]);
    __syncthreads();   // also covers lds_x staging visibility

    float Amr[RRK], Bxr[II], y;
    #pragma unroll
    for (int q = 0; q < RRK; ++q) Amr[q] = ambx[q * 8 + oc];
    #pragma unroll
    for (int i = 0; i < II; ++i) Bxr[i] = ambx[32 + i * 8 + oc];
    y = ambx[96 + oc];

    // ---- pipelined operand state for t=0 ----
    const float* nzp = noise + (size_t)b * (TT * HH) + e0;
    float4 nzb[4];
    #pragma unroll
    for (int j = 0; j < 4; ++j) nzb[j] = *(const float4*)(nzp + (size_t)j * HH);

    float4 xqc0 = *(const float4*)&lds_x[0];
    float4 xqc1 = *(const float4*)&lds_x[4];

    // lagged-y carry state (v_{t-1}, ybase_{t-1})
    float pv0 = 0.f, pv1 = 0.f, pv2 = 0.f, pv3 = 0.f, pyb = 0.f;

    for (int t0 = 0; t0 < TT; t0 += 4) {
        #pragma unroll
        for (int j = 0; j < 4; ++j) {
            const int t = t0 + j;

            // A. issue next-step operand loads early (latency hidden by B-D)
            const int tn = (t + 1 < TT) ? t + 1 : TT - 1;
            const float4 xqn0 = *(const float4*)&lds_x[tn * II];
            const float4 xqn1 = *(const float4*)&lds_x[tn * II + 4];

            // B. v partials from r + in-wave reduction (critical path)
            float vp[RRK];
            #pragma unroll
            for (int q = 0; q < RRK; ++q)
                vp[q] = fmaf(r[0], nr[0][q], fmaf(r[1], nr[1][q],
                        fmaf(r[2], nr[2][q], r[3] * nr[3][q])));
            #pragma unroll
            for (int q = 0; q < RRK; ++q) vp[q] = wave_sum(vp[q]);
            if (lane == 63)
                *(float4*)&red[j][wave][0] = make_float4(vp[0], vp[1], vp[2], vp[3]);

            // C. ybase_t = x_t·Bx[.][oc]  (consumed next iteration)
            float ybase = xqc0.x * Bxr[0];
            ybase = fmaf(xqc0.y, Bxr[1], ybase);
            ybase = fmaf(xqc0.z, Bxr[2], ybase);
            ybase = fmaf(xqc0.w, Bxr[3], ybase);
            ybase = fmaf(xqc1.x, Bxr[4], ybase);
            ybase = fmaf(xqc1.y, Bxr[5], ybase);
            ybase = fmaf(xqc1.z, Bxr[6], ybase);
            ybase = fmaf(xqc1.w, Bxr[7], ybase);

            // D. alpha*u_t
            float au[4];
            #pragma unroll
            for (int e = 0; e < 4; ++e) {
                float a = xqc0.x * wia[0][e];
                a = fmaf(xqc0.y, wia[1][e], a);
                a = fmaf(xqc0.z, wia[2][e], a);
                a = fmaf(xqc0.w, wia[3][e], a);
                a = fmaf(xqc1.x, wia[4][e], a);
                a = fmaf(xqc1.y, wia[5][e], a);
                a = fmaf(xqc1.z, wia[6][e], a);
                au[e] = fmaf(xqc1.w, wia[7][e], a);
            }

            // E. LDS-only barrier (global prefetches stay in flight)
            block_sync_lds();
            // keep the register-only W-block below from being hoisted above
            // the barrier (it would delay barrier arrival instead of filling
            // the ds_read latency shadow)
            __builtin_amdgcn_sched_barrier(0);

            // F. issue cross-wave reads first: v_t partials + W_{t-1} partials
            const float4 s0 = *(const float4*)&red[j][0][0];
            const float4 s1 = *(const float4*)&red[j][1][0];
            const float4 s2 = *(const float4*)&red[j][2][0];
            const float4 s3 = *(const float4*)&red[j][3][0];
            const int jp = (j + 3) & 3;
            const float wr0 = red_w[jp][0][oc];
            const float wr1 = red_w[jp][1][oc];
            const float wr2 = red_w[jp][2][oc];
            const float wr3 = red_w[jp][3][oc];

            // W-block: noise@wo partials for step t (fills the read-latency
            // shadow; consumed at step t+1). Uses nzb[j] BEFORE I overwrites.
            {
                float wp[OO];
                #pragma unroll
                for (int o = 0; o < OO; ++o)
                    wp[o] = fmaf(nzb[j].x, woa[0][o], fmaf(nzb[j].y, woa[1][o],
                            fmaf(nzb[j].z, woa[2][o], nzb[j].w * woa[3][o])));
                #pragma unroll
                for (int o = 0; o < OO; ++o) wp[o] = wave_sum(wp[o]);
                if (lane == 63) {
                    *(float4*)&red_w[j][wave][0] = make_float4(wp[0], wp[1], wp[2], wp[3]);
                    *(float4*)&red_w[j][wave][4] = make_float4(wp[4], wp[5], wp[6], wp[7]);
                }
            }

            // F2. cross-wave v totals (critical)
            const float v0 = (s0.x + s1.x) + (s2.x + s3.x);
            const float v1 = (s0.y + s1.y) + (s2.y + s3.y);
            const float v2 = (s0.z + s1.z) + (s2.z + s3.z);
            const float v3 = (s0.w + s1.w) + (s2.w + s3.w);

            // G. h update
            const float nzv[4] = {nzb[j].x, nzb[j].y, nzb[j].z, nzb[j].w};
            #pragma unroll
            for (int e = 0; e < 4; ++e) {
                float acc = au[e];
                acc = fmaf(v0, ma[e][0], acc);
                acc = fmaf(v1, ma[e][1], acc);
                acc = fmaf(v2, ma[e][2], acc);
                acc = fmaf(v3, ma[e][3], acc);
                h[e] = fmaf(NOISE_STD, nzv[e], fmaf(1.0f - ALPHA, h[e], acc));
            }

            // H'. y recurrence for step t-1 (lagged; off the critical path)
            if (t > 0) {
                const float wr = (wr0 + wr1) + (wr2 + wr3);
                float t4 = fmaf(NOISE_STD, wr, pyb);
                t4 = fmaf(pv0, Amr[0], t4);
                t4 = fmaf(pv1, Amr[1], t4);
                t4 = fmaf(pv2, Amr[2], t4);
                t4 = fmaf(pv3, Amr[3], t4);
                y = fmaf(1.0f - ALPHA, y, t4);
                if (tid < OO) lds_out[(t - 1) * OO + tid] = y;
            }

            // I. noise prefetch for t+4
            {
                int tf = t + 4; if (tf >= TT) tf = 0;
                nzb[j] = *(const float4*)(nzp + (size_t)tf * HH);
            }

            // J. r = tanh(h + b) — critical path to next step
            #pragma unroll
            for (int e = 0; e < 4; ++e)
                r[e] = tanh_from_2x(fmaf(2.0f, h[e], tb2[e]));

            // K. advance operand pipeline + lagged-y carry
            xqc0 = xqn0; xqc1 = xqn1;
            pv0 = v0; pv1 = v1; pv2 = v2; pv3 = v3; pyb = ybase;
        }
    }

    // ---- flush y_{TT-1} (its W partials were written after the last barrier) ----
    block_sync_lds();
    {
        const float wr = (red_w[3][0][oc] + red_w[3][1][oc]) +
                         (red_w[3][2][oc] + red_w[3][3][oc]);
        float t4 = fmaf(NOISE_STD, wr, pyb);
        t4 = fmaf(pv0, Amr[0], t4);
        t4 = fmaf(pv1, Amr[1], t4);
        t4 = fmaf(pv2, Amr[2], t4);
        t4 = fmaf(pv3, Amr[3], t4);
        y = fmaf(1.0f - ALPHA, y, t4);
        if (tid < OO) lds_out[(TT - 1) * OO + tid] = y;
    }

    __syncthreads();
    {
        float4* dst = (float4*)(out + (size_t)b * (TT * OO));
        const float4* srcv = (const float4*)lds_out;
        #pragma unroll
        for (int k = 0; k < 8; ++k)
            dst[k * 256 + tid] = srcv[k * 256 + tid];
    }
}

extern "C" void kernel_launch(void* const* d_in, const int* in_sizes, int n_in,
                              void* d_out, int out_size, void* d_ws, size_t ws_size,
                              hipStream_t stream) {
    const float* x     = (const float*)d_in[0];
    const float* noise = (const float*)d_in[1];
    const float* wi    = (const float*)d_in[2];
    const float* si    = (const float*)d_in[3];
    const float* mM    = (const float*)d_in[4];
    const float* nM    = (const float*)d_in[5];
    const float* bv    = (const float*)d_in[6];
    const float* wo    = (const float*)d_in[7];
    const float* so    = (const float*)d_in[8];
    const float* h0    = (const float*)d_in[9];
    float* out = (float*)d_out;

    rnn_seq_kernel<<<dim3(BB), dim3(256), 0, stream>>>(
        x, noise, wi, si, mM, nM, bv, wo, so, h0, out);
}

// Round 2
// 769.655 us; speedup vs baseline: 1.3358x; 1.3358x over previous
//
#include <hip/hip_runtime.h>

#define BB 64
#define TT 1024
#define HH 1024
#define II 8
#define OO 8
#define RRK 4
#define NOISE_STD 0.05f
#define ALPHA 0.2f

typedef float v4f __attribute__((ext_vector_type(4)));

// 2*log2(e): tanh argument scale so exp goes through native v_exp_f32 (2^x).
#define C2E 2.885390081777927f

// DPP-based add: acc + dpp_perm(src). VALU pipe (NOT ds_bpermute like __shfl).
template<int CTRL, int RM>
__device__ __forceinline__ float dpp_add(float acc, float src) {
    int s = __builtin_amdgcn_update_dpp(0, __float_as_int(src), CTRL, RM, 0xF, true);
    return acc + __int_as_float(s);
}

// Full wave64 sum; result valid on lane 63.
__device__ __forceinline__ float wave_sum(float x) {
    x = dpp_add<0xB1, 0xF>(x, x);   // xor 1
    x = dpp_add<0x4E, 0xF>(x, x);   // xor 2
    x = dpp_add<0x141, 0xF>(x, x);  // row_half_mirror
    x = dpp_add<0x140, 0xF>(x, x);  // row_mirror
    x = dpp_add<0x142, 0xA>(x, x);  // row_bcast:15
    x = dpp_add<0x143, 0xC>(x, x);  // row_bcast:31
    return x;
}

// tanh(x) = 1 - 2/(1 + 2^(2x*log2e)); argument passed as 2x*log2(e).
__device__ __forceinline__ float tanh_from_l2x(float l2x) {
    float e = __builtin_amdgcn_exp2f(l2x);
    float r = __builtin_amdgcn_rcpf(e + 1.0f);
    return fmaf(-2.0f, r, 1.0f);
}

// Barrier WITHOUT the vmcnt(0) drain of __syncthreads(): waits only LDS ops.
__device__ __forceinline__ void block_sync_lds() {
    asm volatile("s_waitcnt lgkmcnt(0)\n\ts_barrier" ::: "memory");
}

// ---------------------------------------------------------------------------
// Pre-kernel: W[row][o] = NOISE_STD * sum_h noise[row,h] * wo[h][o]*so[o]
// row = b*TT + t, 65536 rows. 8-row phases + 2-deep ring on the reduction
// buffer -> ONE barrier per phase (4/block instead of 16) and 8 independent
// DPP-chain rows per segment for ILP. Target: approach the 44 us BW floor.
// ---------------------------------------------------------------------------
__global__ __launch_bounds__(256)
void prew_kernel(const float* __restrict__ noise, const float* __restrict__ wo,
                 const float* __restrict__ so, float* __restrict__ W) {
    __shared__ __align__(16) float red[2][8][4][8];   // ring x row x wave x o

    const int tid  = threadIdx.x;
    const int wave = tid >> 6;
    const int lane = tid & 63;
    const int e0   = tid << 2;                        // h = e0..e0+3

    float woa[4][OO];
    {
        float so8[OO];
        #pragma unroll
        for (int o = 0; o < OO; ++o) so8[o] = so[o] * NOISE_STD;
        #pragma unroll
        for (int e = 0; e < 4; ++e) {
            const float4 a4 = *(const float4*)(wo + (e0 + e) * OO);
            const float4 b4 = *(const float4*)(wo + (e0 + e) * OO + 4);
            woa[e][0] = a4.x * so8[0]; woa[e][1] = a4.y * so8[1];
            woa[e][2] = a4.z * so8[2]; woa[e][3] = a4.w * so8[3];
            woa[e][4] = b4.x * so8[4]; woa[e][5] = b4.y * so8[5];
            woa[e][6] = b4.z * so8[6]; woa[e][7] = b4.w * so8[7];
        }
    }

    const int row0 = blockIdx.x * 32;
    #pragma unroll
    for (int ph = 0; ph < 4; ++ph) {
        const int cur   = ph & 1;
        const int rbase = row0 + ph * 8;

        float4 nz[8];
        #pragma unroll
        for (int j = 0; j < 8; ++j)
            nz[j] = *(const float4*)(noise + (size_t)(rbase + j) * HH + e0);

        #pragma unroll
        for (int j = 0; j < 8; ++j) {
            float op[OO];
            #pragma unroll
            for (int o = 0; o < OO; ++o)
                op[o] = fmaf(nz[j].x, woa[0][o], fmaf(nz[j].y, woa[1][o],
                        fmaf(nz[j].z, woa[2][o], nz[j].w * woa[3][o])));
            #pragma unroll
            for (int o = 0; o < OO; ++o) op[o] = wave_sum(op[o]);
            if (lane == 63) {
                *(float4*)&red[cur][j][wave][0] = make_float4(op[0], op[1], op[2], op[3]);
                *(float4*)&red[cur][j][wave][4] = make_float4(op[4], op[5], op[6], op[7]);
            }
        }
        block_sync_lds();
        if (tid < 64) {
            const int j = tid >> 3, o = tid & 7;
            W[(rbase + j) * OO + o] = (red[cur][j][0][o] + red[cur][j][1][o]) +
                                      (red[cur][j][2][o] + red[cur][j][3][o]);
        }
        // no trailing barrier: next phase writes the OTHER ring slot; the
        // lgkmcnt(0) in the NEXT phase's barrier orders these reads before
        // the phase-after-next reuses this slot.
    }
}

// ---------------------------------------------------------------------------
// Main RNN kernel: one block per batch; out via 8-dim y-recurrence.
// v4f (ext_vector) math over the 4 hidden elems/thread -> v_pk_fma_f32.
// ---------------------------------------------------------------------------
__global__ __launch_bounds__(256, 1)
void rnn_seq_kernel(const float* __restrict__ x, const float* __restrict__ noise,
                    const float* __restrict__ wi, const float* __restrict__ si,
                    const float* __restrict__ mM, const float* __restrict__ nM,
                    const float* __restrict__ bv, const float* __restrict__ wo,
                    const float* __restrict__ so, const float* __restrict__ h0,
                    const float* __restrict__ W, float* __restrict__ out) {
    __shared__ __align__(16) float lds_x[(TT + 1) * II]; // 32.03 KB (+1 pad row)
    __shared__ __align__(16) float lds_W[TT * OO];    // 32 KB (sigma-scaled noise@woa)
    __shared__ __align__(16) float lds_out[TT * OO];  // 32 KB
    __shared__ __align__(16) float red[4][4][4];      // ring x wave x q
    __shared__ __align__(16) float redc[4][104];      // preamble scratch (wave-major)
    __shared__ float ambx[104];                       // Am(32) | Bx(64) | y0(8)

    const int tid  = threadIdx.x;
    const int b    = blockIdx.x;
    const int wave = tid >> 6;
    const int lane = tid & 63;
    const int e0   = tid << 2;
    const int oc   = tid & 7;                         // this thread's o-column for y

    // ---- stage x[b] and W[b] into LDS ----
    {
        const float4* sx = (const float4*)(x + (size_t)b * (TT * II));
        const float4* sw = (const float4*)(W + (size_t)b * (TT * OO));
        float4* dx = (float4*)lds_x;
        float4* dw = (float4*)lds_W;
        #pragma unroll
        for (int k = 0; k < 8; ++k) {
            dx[k * 256 + tid] = sx[k * 256 + tid];
            dw[k * 256 + tid] = sw[k * 256 + tid];
        }
        if (tid < 2) dx[2048 + tid] = sx[2046 + tid];  // pad row TT = row TT-1
    }

    // ---- fold constants into registers ----
    float wia[II][4];                                  // ALPHA*si[i]*wi[i][h_e]
    v4f   wiac[II];                                    // same, as v4 over e
    #pragma unroll
    for (int i = 0; i < II; ++i) {
        const float s  = ALPHA * si[i];
        const float4 w = *(const float4*)(wi + i * HH + e0);
        wia[i][0] = w.x * s; wia[i][1] = w.y * s; wia[i][2] = w.z * s; wia[i][3] = w.w * s;
        wiac[i] = (v4f){wia[i][0], wia[i][1], wia[i][2], wia[i][3]};
    }
    float ma[4][RRK];
    v4f   nrv[4];                                      // nr row e as v4 over q
    v4f   mac[RRK];                                    // ma column q as v4 over e
    #pragma unroll
    for (int e = 0; e < 4; ++e) {
        const float4 m4 = *(const float4*)(mM + (e0 + e) * RRK);
        const float4 n4 = *(const float4*)(nM + (e0 + e) * RRK);
        const float cs = ALPHA / (float)HH;            // fold ALPHA/H into m
        ma[e][0] = m4.x * cs; ma[e][1] = m4.y * cs; ma[e][2] = m4.z * cs; ma[e][3] = m4.w * cs;
        nrv[e] = (v4f){n4.x, n4.y, n4.z, n4.w};
    }
    #pragma unroll
    for (int q = 0; q < RRK; ++q)
        mac[q] = (v4f){ma[0][q], ma[1][q], ma[2][q], ma[3][q]};

    float woa[4][OO];                                  // wo[h_e][o]*so[o]  (preamble only)
    {
        float so8[OO];
        #pragma unroll
        for (int o = 0; o < OO; ++o) so8[o] = so[o];
        #pragma unroll
        for (int e = 0; e < 4; ++e) {
            const float4 a4 = *(const float4*)(wo + (e0 + e) * OO);
            const float4 b4 = *(const float4*)(wo + (e0 + e) * OO + 4);
            woa[e][0] = a4.x * so8[0]; woa[e][1] = a4.y * so8[1];
            woa[e][2] = a4.z * so8[2]; woa[e][3] = a4.w * so8[3];
            woa[e][4] = b4.x * so8[4]; woa[e][5] = b4.y * so8[5];
            woa[e][6] = b4.z * so8[6]; woa[e][7] = b4.w * so8[7];
        }
    }
    v4f tb2e, h, r;
    {
        const v4f b4 = *(const v4f*)(bv + e0);
        tb2e = C2E * b4;                               // (2*log2e)*b
        h = *(const v4f*)(h0 + e0);
        v4f targ = C2E * h;
        r.x = tanh_from_l2x(targ.x); r.y = tanh_from_l2x(targ.y);
        r.z = tanh_from_l2x(targ.z); r.w = tanh_from_l2x(targ.w);
    }

    // ---- preamble: reduce Am (4x8), Bx (8x8), y0 (8) from register-folded weights ----
    // outputs k: [0,32) Am[q=k>>3][o=k&7]; [32,96) Bx[i=(k-32)>>3][o]; [96,104) y0[o]
    #pragma unroll
    for (int kg = 0; kg < 26; ++kg) {
        float p[4];
        #pragma unroll
        for (int u = 0; u < 4; ++u) {
            const int k = kg * 4 + u;
            float s;
            if (k < 32) {
                const int q = k >> 3, o = k & 7;
                s = fmaf(ma[0][q], woa[0][o], fmaf(ma[1][q], woa[1][o],
                    fmaf(ma[2][q], woa[2][o], ma[3][q] * woa[3][o])));
            } else if (k < 96) {
                const int i = (k - 32) >> 3, o = k & 7;
                s = fmaf(wia[i][0], woa[0][o], fmaf(wia[i][1], woa[1][o],
                    fmaf(wia[i][2], woa[2][o], wia[i][3] * woa[3][o])));
            } else {
                const int o = k - 96;
                s = fmaf(h.x, woa[0][o], fmaf(h.y, woa[1][o],
                    fmaf(h.z, woa[2][o], h.w * woa[3][o])));
            }
            p[u] = wave_sum(s);
        }
        if (lane == 63)
            *(float4*)&redc[wave][kg * 4] = make_float4(p[0], p[1], p[2], p[3]);
    }
    block_sync_lds();
    if (tid < 104)
        ambx[tid] = (redc[0][tid] + redc[1][tid]) + (redc[2][tid] + redc[3][tid]);
    __syncthreads();   // also covers lds_x / lds_W staging visibility

    float Amr[RRK], Bxr[II], y;
    #pragma unroll
    for (int q = 0; q < RRK; ++q) Amr[q] = ambx[q * 8 + oc];
    #pragma unroll
    for (int i = 0; i < II; ++i) Bxr[i] = ambx[32 + i * 8 + oc];
    y = ambx[96 + oc];

    // ---- pipelined operand state for t=0 ----
    const float* nzp = noise + (size_t)b * (TT * HH) + e0;
    v4f nzb[4];
    #pragma unroll
    for (int j = 0; j < 4; ++j) nzb[j] = *(const v4f*)(nzp + j * HH);

    v4f xqc0 = *(const v4f*)&lds_x[0];
    v4f xqc1 = *(const v4f*)&lds_x[4];
    float wqc = lds_W[oc];

    for (int t0 = 0; t0 < TT; t0 += 4) {
        #pragma unroll
        for (int j = 0; j < 4; ++j) {
            const int t = t0 + j;

            // A. issue next-step operand loads early (pad row makes t+1 safe)
            const int tn = t + 1;
            const v4f xqn0 = *(const v4f*)&lds_x[tn * II];
            const v4f xqn1 = *(const v4f*)&lds_x[tn * II + 4];
            const float wqn = lds_W[(tn & (TT - 1)) * OO + oc];

            // B. v partials from r + in-wave reduction (packed FMA)
            v4f vpv = r.x * nrv[0];
            vpv += r.y * nrv[1];
            vpv += r.z * nrv[2];
            vpv += r.w * nrv[3];
            float vp0 = wave_sum(vpv.x);
            float vp1 = wave_sum(vpv.y);
            float vp2 = wave_sum(vpv.z);
            float vp3 = wave_sum(vpv.w);
            if (lane == 63)
                *(float4*)&red[j][wave][0] = make_float4(vp0, vp1, vp2, vp3);

            // C. ybase = x_t·Bx[.][oc] + W_t[oc]  (v-independent part of y)
            float ybase = fmaf(xqc0.x, Bxr[0], wqc);
            ybase = fmaf(xqc0.y, Bxr[1], ybase);
            ybase = fmaf(xqc0.z, Bxr[2], ybase);
            ybase = fmaf(xqc0.w, Bxr[3], ybase);
            ybase = fmaf(xqc1.x, Bxr[4], ybase);
            ybase = fmaf(xqc1.y, Bxr[5], ybase);
            ybase = fmaf(xqc1.z, Bxr[6], ybase);
            ybase = fmaf(xqc1.w, Bxr[7], ybase);

            // D. alpha*u_t (packed FMA over the 4 hidden elems)
            v4f auv = xqc0.x * wiac[0];
            auv += xqc0.y * wiac[1];
            auv += xqc0.z * wiac[2];
            auv += xqc0.w * wiac[3];
            auv += xqc1.x * wiac[4];
            auv += xqc1.y * wiac[5];
            auv += xqc1.z * wiac[6];
            auv += xqc1.w * wiac[7];

            // E. LDS-only barrier (global prefetches stay in flight)
            block_sync_lds();

            // F. cross-wave v totals (packed adds)
            const v4f s0 = *(const v4f*)&red[j][0][0];
            const v4f s1 = *(const v4f*)&red[j][1][0];
            const v4f s2 = *(const v4f*)&red[j][2][0];
            const v4f s3 = *(const v4f*)&red[j][3][0];
            const v4f vs = (s0 + s1) + (s2 + s3);

            // G. h update (packed FMA)
            v4f acc = auv;
            acc += vs.x * mac[0];
            acc += vs.y * mac[1];
            acc += vs.z * mac[2];
            acc += vs.w * mac[3];
            h = (1.0f - ALPHA) * h + acc;
            h += NOISE_STD * nzb[j];

            // H. y recurrence (all lanes compute column oc; tid<8 writes)
            {
                float t4 = fmaf(vs.x, Amr[0], ybase);
                t4 = fmaf(vs.y, Amr[1], t4);
                t4 = fmaf(vs.z, Amr[2], t4);
                t4 = fmaf(vs.w, Amr[3], t4);
                y = fmaf(1.0f - ALPHA, y, t4);
                if (tid < OO) lds_out[t * OO + tid] = y;
            }

            // I. noise prefetch for t+4 (wrap via mask; wrapped rows unused)
            nzb[j] = *(const v4f*)(nzp + ((t + 4) & (TT - 1)) * HH);

            // J. r = tanh(h + b) — critical path to next step (exp2-native)
            {
                v4f targ = C2E * h + tb2e;
                r.x = tanh_from_l2x(targ.x);
                r.y = tanh_from_l2x(targ.y);
                r.z = tanh_from_l2x(targ.z);
                r.w = tanh_from_l2x(targ.w);
            }

            // K. advance operand pipeline
            xqc0 = xqn0; xqc1 = xqn1; wqc = wqn;
        }
    }

    __syncthreads();
    {
        float4* dst = (float4*)(out + (size_t)b * (TT * OO));
        const float4* srcv = (const float4*)lds_out;
        #pragma unroll
        for (int k = 0; k < 8; ++k)
            dst[k * 256 + tid] = srcv[k * 256 + tid];
    }
}

extern "C" void kernel_launch(void* const* d_in, const int* in_sizes, int n_in,
                              void* d_out, int out_size, void* d_ws, size_t ws_size,
                              hipStream_t stream) {
    const float* x     = (const float*)d_in[0];
    const float* noise = (const float*)d_in[1];
    const float* wi    = (const float*)d_in[2];
    const float* si    = (const float*)d_in[3];
    const float* mM    = (const float*)d_in[4];
    const float* nM    = (const float*)d_in[5];
    const float* bv    = (const float*)d_in[6];
    const float* wo    = (const float*)d_in[7];
    const float* so    = (const float*)d_in[8];
    const float* h0    = (const float*)d_in[9];
    float* out = (float*)d_out;
    float* W   = (float*)d_ws;   // 65536 x 8 fp32 = 2 MB

    prew_kernel<<<dim3(2048), dim3(256), 0, stream>>>(noise, wo, so, W);
    rnn_seq_kernel<<<dim3(BB), dim3(256), 0, stream>>>(
        x, noise, wi, si, mM, nM, bv, wo, so, h0, W, out);
}